// Round 6
// baseline (277.633 us; speedup 1.0000x reference)
//
#include <hip/hip_runtime.h>

// MRGCO: real-FFT tensor-product RGCN layer.
// real(fft) along k (len 8) = rank-5 cosine transform (j and 8-j rows equal);
// the ifft->fft round-trip between the two tensor products cancels exactly.
// Pipeline: k_pre (A->Af 8m/thread NT reads, X->Xft LDS transpose, W->Wft;
// bf16 XOR-swizzled layouts) ; gemm_lds<BH=64> C1=Af@Xft (320 blocks) ;
// gemm_lds<BH=128> C2=C1@Wft ; k_combine.
//
// Swizzle: logical (row r, col c) of a K-contiguous operand stored at
//   r*K + (c&~63) + ((((c>>3)&7) ^ (r&7))<<3) + (c&7)
// so a LINEAR wave-uniform global_load_lds DMA lands tiles in LDS already
// bank-swizzled; ds_read_b128 fragment reads stay conflict-free.
// GEMM K-loop: double-buffered LDS, raw s_barrier + manual s_waitcnt vmcnt(N)
// so the next tile's DMA stays in flight across the barrier (AITER-style).

typedef __bf16 bf16_t;
typedef __bf16 bf16x2 __attribute__((ext_vector_type(2)));
typedef __bf16 bf16x8 __attribute__((ext_vector_type(8)));
typedef float f32x4 __attribute__((ext_vector_type(4)));

#define R2C 0.70710678118654752f

__device__ __forceinline__ size_t swz(int r, int c, int K) {
  return (size_t)r * K + (c & ~63) + ((((c >> 3) & 7) ^ (r & 7)) << 3) + (c & 7);
}

__device__ __forceinline__ void async_cp16(const void* g, void* l) {
  __builtin_amdgcn_global_load_lds((const __attribute__((address_space(1))) char*)g,
                                   (__attribute__((address_space(3))) char*)l,
                                   16, 0, 0);
}

__device__ __forceinline__ void fwd5(const float x[8], float F[5]) {
  float s04 = x[0] + x[4], d04 = x[0] - x[4];
  float s26 = x[2] + x[6];
  float s15 = x[1] + x[5], s37 = x[3] + x[7];
  float t = (x[1] + x[7]) - (x[3] + x[5]);
  float e = s04 + s26, o = s15 + s37;
  F[0] = e + o;
  F[1] = d04 + R2C * t;
  F[2] = s04 - s26;
  F[3] = d04 - R2C * t;
  F[4] = e - o;
}

// Fused input transforms. blocks [0,2048): A ; [2048,2304): X ; [2304,2560): W.
__global__ __launch_bounds__(256) void k_pre(const float* __restrict__ X,
                                             const float* __restrict__ A,
                                             const float* __restrict__ W,
                                             bf16_t* __restrict__ Xft,
                                             bf16_t* __restrict__ Af,
                                             bf16_t* __restrict__ Wft) {
  __shared__ bf16_t tx[40][256];  // X transpose staging: [j*8+h][m]
  int b = blockIdx.x;
  if (b < 2048) {
    // Af[j][n][m] swizzled; 8 consecutive m per thread -> one full 16B chunk
    // per plane. 256B contiguous nontemporal reads (A is stream-once).
    size_t t = (size_t)b * 256 + threadIdx.x;
    size_t idx = t * 8;  // n*2048 + m, m 8-aligned
    int n = (int)(idx >> 11), m8 = (int)(idx & 2047);
    const f32x4* p = (const f32x4*)(A + idx * 8);
    float F[8][5];
#pragma unroll
    for (int u = 0; u < 8; u++) {
      f32x4 a = __builtin_nontemporal_load(p + 2 * u);
      f32x4 bb = __builtin_nontemporal_load(p + 2 * u + 1);
      float x[8] = {a.x, a.y, a.z, a.w, bb.x, bb.y, bb.z, bb.w};
      fwd5(x, F[u]);
    }
    size_t pos = (size_t)n * 2048 + (m8 & ~63) + ((((m8 >> 3) & 7) ^ (n & 7)) << 3);
#pragma unroll
    for (int j = 0; j < 5; j++) {
      bf16x8 v = {(bf16_t)F[0][j], (bf16_t)F[1][j], (bf16_t)F[2][j],
                  (bf16_t)F[3][j], (bf16_t)F[4][j], (bf16_t)F[5][j],
                  (bf16_t)F[6][j], (bf16_t)F[7][j]};
      *(bf16x8*)(Af + (size_t)j * 4194304 + pos) = v;
    }
  } else if (b < 2304) {
    // Xft[j][h][m]: tile 256 m x 8 h. Coalesced reads -> LDS -> full 16B
    // swizzled chunk writes.
    int bx = b - 2048;
    int m0 = (bx & 7) * 256, h0 = (bx >> 3) * 8;
    int t = threadIdx.x;
    const float4* p = (const float4*)(X + (((size_t)(m0 + t) * 256) + h0) * 8);
#pragma unroll
    for (int h = 0; h < 8; h++) {
      float4 a = p[2 * h], bb = p[2 * h + 1];
      float x[8] = {a.x, a.y, a.z, a.w, bb.x, bb.y, bb.z, bb.w};
      float F[5];
      fwd5(x, F);
#pragma unroll
      for (int j = 0; j < 5; j++) tx[j * 8 + h][t] = (bf16_t)F[j];
    }
    __syncthreads();
#pragma unroll
    for (int it = 0; it < 5; it++) {
      int slot = it * 256 + t;
      int row = slot >> 5, ch = slot & 31;
      int j = row >> 3, hl = row & 7;
      int h = h0 + hl;
      size_t gpos = (size_t)j * 524288 + (size_t)h * 2048 + m0 +
                    ((ch & ~7) << 3) + (((ch & 7) ^ (h & 7)) << 3);
      *(uint4*)(Xft + gpos) = *(const uint4*)(&tx[row][ch * 8]);
    }
  } else {
    // Wft[j][h][h'] = s_j * sum_k W[h'][h][k] c_jk, swizzled (tiny)
    int h = b - 2304;
    int hp = threadIdx.x;
    const float4* p = (const float4*)(W + ((size_t)hp * 256 + h) * 8);
    float4 a = p[0], bb = p[1];
    float x[8] = {a.x, a.y, a.z, a.w, bb.x, bb.y, bb.z, bb.w};
    float F[5];
    fwd5(x, F);
    const float sc[5] = {0.125f, 0.25f, 0.25f, 0.25f, 0.125f};
    size_t pos = swz(h, hp, 256);
#pragma unroll
    for (int j = 0; j < 5; j++)
      Wft[(size_t)j * 65536 + pos] = (bf16_t)(F[j] * sc[j]);
  }
}

// Batched bf16 GEMM, 128 x BH tile, BK=64, 4 waves (64 x BH/2 each), 16x16x32
// MFMA. Swizzled operands; global_load_lds width-16 staging, double-buffered
// LDS, raw s_barrier + manual vmcnt so prefetch stays in flight across barriers.
template <typename OutT, bool SWZ_OUT, int BH>
__global__ __launch_bounds__(256) void gemm_lds(const bf16_t* __restrict__ A,
                                                const bf16_t* __restrict__ B,
                                                OutT* __restrict__ C, int K,
                                                size_t ap, size_t bp, size_t cp) {
  constexpr int WH = BH / 2;    // wave h-tile
  constexpr int NT = WH / 16;   // B frags / acc cols per wave
  constexpr int BR = BH / 32;   // B staging rounds (A rounds = 4)
  constexpr int ABUF = 128 * 64;
  constexpr int BBUF = BH * 64;
  __shared__ bf16_t sm[2 * ABUF + 2 * BBUF];  // A0 A1 B0 B1
  const int j = blockIdx.z;
  const bf16_t* Aj = A + (size_t)j * ap;
  const bf16_t* Bj = B + (size_t)j * bp;
  OutT* Cj = C + (size_t)j * cp;
  const int n0 = blockIdx.x * 128, h0 = blockIdx.y * BH;
  const int tid = threadIdx.x;
  const int wv = tid >> 6, ln = tid & 63;
  const int quad = ln >> 4, l16 = ln & 15;
  const int wn = (wv & 1) * 64, wh = (wv >> 1) * WH;

  const bf16_t* ga[4];
  int loA[4];
#pragma unroll
  for (int s = 0; s < 4; s++) {
    int slot = s * 256 + tid;
    int row = slot >> 3, c16 = slot & 7;
    ga[s] = Aj + (size_t)(n0 + row) * K + c16 * 8;
    loA[s] = (s * 256 + wv * 64) * 8;
  }
  const bf16_t* gb[BR];
  int loB[BR];
#pragma unroll
  for (int s = 0; s < BR; s++) {
    int slot = s * 256 + tid;
    int row = slot >> 3, c16 = slot & 7;
    gb[s] = Bj + (size_t)(h0 + row) * K + c16 * 8;
    loB[s] = (s * 256 + wv * 64) * 8;
  }

  // prologue: tile 0 -> buffer 0
#pragma unroll
  for (int s = 0; s < 4; s++) async_cp16(ga[s], sm + loA[s]);
#pragma unroll
  for (int s = 0; s < BR; s++) async_cp16(gb[s], sm + 2 * ABUF + loB[s]);

  f32x4 acc[4][NT] = {};
  for (int kk = 0; kk < K; kk += 64) {
    int p = (kk >> 6) & 1;
    if (kk + 64 < K) {
#pragma unroll
      for (int s = 0; s < 4; s++)
        async_cp16(ga[s] + kk + 64, sm + (p ^ 1) * ABUF + loA[s]);
#pragma unroll
      for (int s = 0; s < BR; s++)
        async_cp16(gb[s] + kk + 64, sm + 2 * ABUF + (p ^ 1) * BBUF + loB[s]);
      __builtin_amdgcn_s_waitcnt(0xF70 | (4 + BR));  // tile kk landed
    } else {
      __builtin_amdgcn_s_waitcnt(0xF70);  // vmcnt(0)
    }
    __builtin_amdgcn_s_barrier();
    const bf16_t* Asp = sm + p * ABUF;
    const bf16_t* Bsp = sm + 2 * ABUF + p * BBUF;
#pragma unroll
    for (int kh = 0; kh < 2; kh++) {
      bf16x8 af[4], bfr[NT];
      int c16 = kh * 4 + quad;
#pragma unroll
      for (int i = 0; i < 4; i++) {
        int ra = wn + i * 16 + l16;
        af[i] = *(const bf16x8*)(Asp + ra * 64 + ((c16 ^ (ra & 7)) << 3));
      }
#pragma unroll
      for (int t = 0; t < NT; t++) {
        int rb = wh + t * 16 + l16;
        bfr[t] = *(const bf16x8*)(Bsp + rb * 64 + ((c16 ^ (rb & 7)) << 3));
      }
#pragma unroll
      for (int i = 0; i < 4; i++)
#pragma unroll
        for (int t = 0; t < NT; t++)
          acc[i][t] = __builtin_amdgcn_mfma_f32_16x16x32_bf16(af[i], bfr[t],
                                                              acc[i][t], 0, 0, 0);
    }
    __builtin_amdgcn_s_barrier();  // protect buffer p^1 before next-iter DMA
  }
  // C/D layout: col = lane&15, row = quad*4 + reg
#pragma unroll
  for (int i = 0; i < 4; i++) {
#pragma unroll
    for (int t = 0; t < NT; t++) {
      int hc = h0 + wh + t * 16 + l16;
#pragma unroll
      for (int rg = 0; rg < 4; rg++) {
        int nr = n0 + wn + i * 16 + quad * 4 + rg;
        size_t off = SWZ_OUT ? swz(nr, hc, 256) : (size_t)nr * 256 + hc;
        Cj[off] = (OutT)acc[i][t][rg];
      }
    }
  }
}

// out[n][h][k] = sum_j c_jk * C2_j[n][h]  (ifft scales folded into Wft)
__global__ __launch_bounds__(256) void k_combine(const float* __restrict__ C2,
                                                 float* __restrict__ out) {
  size_t idx = (size_t)blockIdx.x * 256 + threadIdx.x;
  float c0 = C2[idx];
  float c1 = C2[524288 + idx];
  float c2 = C2[2 * 524288 + idx];
  float c3 = C2[3 * 524288 + idx];
  float c4 = C2[4 * 524288 + idx];
  float o0 = c0 + c1 + c2 + c3 + c4;
  float o4 = c0 - c1 + c2 - c3 + c4;
  float o2 = c0 - c2 + c4;
  float rt = R2C * (c1 - c3);
  float o1 = c0 + rt - c4;
  float o3 = c0 - rt - c4;
  float4* op = (float4*)(out + idx * 8);
  op[0] = make_float4(o0, o1, o2, o3);
  op[1] = make_float4(o4, o3, o2, o1);
}

extern "C" void kernel_launch(void* const* d_in, const int* in_sizes, int n_in,
                              void* d_out, int out_size, void* d_ws, size_t ws_size,
                              hipStream_t stream) {
  const float* X = (const float*)d_in[0];   // (2048,256,8)
  const float* A = (const float*)d_in[1];   // (2048,2048,8)
  const float* W = (const float*)d_in[2];   // (256,256,8)
  float* out = (float*)d_out;               // (2048,256,8)
  char* ws = (char*)d_ws;

  bf16_t* Af  = (bf16_t*)(ws);              // 5*2048*2048*2 = 41943040
  bf16_t* Xft = (bf16_t*)(ws + 41943040);   // 5*256*2048*2  =  5242880
  bf16_t* Wft = (bf16_t*)(ws + 47185920);   // 5*256*256*2   =   655360
  bf16_t* C1  = (bf16_t*)(ws + 47841280);   // 5*2048*256*2  =  5242880
  float*  C2  = (float*) (ws + 53084160);   // 5*2048*256*4  = 10485760
                                            // total 63569920 B

  k_pre<<<dim3(2560), 256, 0, stream>>>(X, A, W, Xft, Af, Wft);
  // gemm1: 128x64 tiles -> 320 blocks (full CU coverage for the A-stream)
  gemm_lds<bf16_t, true, 64><<<dim3(16, 4, 5), 256, 0, stream>>>(
      Af, Xft, C1, 2048, (size_t)4194304, (size_t)524288, (size_t)524288);
  // gemm2: K=256, 128x128 tiles
  gemm_lds<float, false, 128><<<dim3(16, 2, 5), 256, 0, stream>>>(
      C1, Wft, C2, 256, (size_t)524288, (size_t)65536, (size_t)524288);
  k_combine<<<dim3(2048), 256, 0, stream>>>(C2, out);
}

// Round 7
// 258.415 us; speedup vs baseline: 1.0744x; 1.0744x over previous
//
#include <hip/hip_runtime.h>

// MRGCO: real-FFT tensor-product RGCN layer.
// real(fft) along k (len 8) = rank-5 cosine transform (j and 8-j rows equal);
// the ifft->fft round-trip between the two tensor products cancels exactly.
// Pipeline: k_pre (A->Af via dual LDS transpose, X->Xft LDS transpose, W->Wft;
// bf16 XOR-swizzled layouts) ; gemm_lds<BH=128> C1=Af@Xft ; gemm_lds<BH=128>
// C2=C1@Wft ; k_combine.
//
// Swizzle: logical (row r, col c) of a K-contiguous operand stored at
//   r*K + (c&~63) + ((((c>>3)&7) ^ (r&7))<<3) + (c&7)
// so a LINEAR wave-uniform global_load_lds DMA lands tiles in LDS already
// bank-swizzled; ds_read_b128 fragment reads stay conflict-free.
// GEMM K-loop: double-buffered LDS, raw s_barrier + manual s_waitcnt vmcnt(N)
// so the next tile's DMA stays in flight across the barrier (AITER-style).
// k_pre A-path: EVERY global access is lane-stride-16B (full-line L2
// transactions) — the R3..R6 k_pre was stuck at ~2 TB/s because 64-256B/lane
// strides used only 16B per touched line.

typedef __bf16 bf16_t;
typedef __bf16 bf16x2 __attribute__((ext_vector_type(2)));
typedef __bf16 bf16x8 __attribute__((ext_vector_type(8)));
typedef float f32x4 __attribute__((ext_vector_type(4)));

#define R2C 0.70710678118654752f

__device__ __forceinline__ size_t swz(int r, int c, int K) {
  return (size_t)r * K + (c & ~63) + ((((c >> 3) & 7) ^ (r & 7)) << 3) + (c & 7);
}

__device__ __forceinline__ void async_cp16(const void* g, void* l) {
  __builtin_amdgcn_global_load_lds((const __attribute__((address_space(1))) char*)g,
                                   (__attribute__((address_space(3))) char*)l,
                                   16, 0, 0);
}

__device__ __forceinline__ void fwd5(const float x[8], float F[5]) {
  float s04 = x[0] + x[4], d04 = x[0] - x[4];
  float s26 = x[2] + x[6];
  float s15 = x[1] + x[5], s37 = x[3] + x[7];
  float t = (x[1] + x[7]) - (x[3] + x[5]);
  float e = s04 + s26, o = s15 + s37;
  F[0] = e + o;
  F[1] = d04 + R2C * t;
  F[2] = s04 - s26;
  F[3] = d04 - R2C * t;
  F[4] = e - o;
}

// Fused input transforms. blocks [0,2048): A ; [2048,2304): X ; [2304,2560): W.
__global__ __launch_bounds__(256) void k_pre(const float* __restrict__ X,
                                             const float* __restrict__ A,
                                             const float* __restrict__ W,
                                             bf16_t* __restrict__ Xft,
                                             bf16_t* __restrict__ Af,
                                             bf16_t* __restrict__ Wft) {
  __shared__ __align__(16) char sm_raw[28672];  // A: 8KB stage + 20KB out; X: 20KB
  int b = blockIdx.x;
  int t = threadIdx.x;
  if (b < 2048) {
    // A-path: block = one n-row (2048 m). 8 rounds x 256 elems.
    // Coalesced float4 reads (lane stride 16B) -> LDS [k][e] -> per-thread
    // k-vector -> fwd5 -> bf16 out-buffer -> swizzled 16B-chunk flush.
    float* st = (float*)sm_raw;                    // [8][256] floats
    bf16_t* ob = (bf16_t*)(sm_raw + 8192);         // [5][2048] bf16
    const int n = b;
    const f32x4* Arow = (const f32x4*)(A + (size_t)n * 16384);
#pragma unroll 1
    for (int r = 0; r < 8; r++) {
      f32x4 q0 = Arow[r * 512 + t];
      f32x4 q1 = Arow[r * 512 + 256 + t];
      __syncthreads();  // previous round's st reads complete
      {
        int e0 = t >> 1, h0 = (t & 1) * 4;
        st[(h0 + 0) * 256 + e0] = q0.x;
        st[(h0 + 1) * 256 + e0] = q0.y;
        st[(h0 + 2) * 256 + e0] = q0.z;
        st[(h0 + 3) * 256 + e0] = q0.w;
        int e1 = e0 + 128;
        st[(h0 + 0) * 256 + e1] = q1.x;
        st[(h0 + 1) * 256 + e1] = q1.y;
        st[(h0 + 2) * 256 + e1] = q1.z;
        st[(h0 + 3) * 256 + e1] = q1.w;
      }
      __syncthreads();
      float x[8];
#pragma unroll
      for (int k = 0; k < 8; k++) x[k] = st[k * 256 + t];
      float F[5];
      fwd5(x, F);
#pragma unroll
      for (int j = 0; j < 5; j++) ob[j * 2048 + r * 256 + t] = (bf16_t)F[j];
    }
    __syncthreads();
    // flush: thread t, plane j -> 16B chunk covering m = t*8..t*8+7
#pragma unroll
    for (int j = 0; j < 5; j++) {
      uint4 v = *(const uint4*)(ob + j * 2048 + t * 8);
      size_t gpos = (size_t)j * 4194304 + (size_t)n * 2048 + ((t * 8) & ~63) +
                    (((t & 7) ^ (n & 7)) << 3);
      *(uint4*)(Af + gpos) = v;
    }
  } else if (b < 2304) {
    // Xft[j][h][m]: tile 256 m x 8 h. reads -> LDS -> full 16B swizzled writes.
    bf16_t* tx = (bf16_t*)sm_raw;  // [40][256]
    int bx = b - 2048;
    int m0 = (bx & 7) * 256, h0 = (bx >> 3) * 8;
    const float4* p = (const float4*)(X + (((size_t)(m0 + t) * 256) + h0) * 8);
#pragma unroll
    for (int h = 0; h < 8; h++) {
      float4 a = p[2 * h], bb = p[2 * h + 1];
      float x[8] = {a.x, a.y, a.z, a.w, bb.x, bb.y, bb.z, bb.w};
      float F[5];
      fwd5(x, F);
#pragma unroll
      for (int j = 0; j < 5; j++) tx[(j * 8 + h) * 256 + t] = (bf16_t)F[j];
    }
    __syncthreads();
#pragma unroll
    for (int it = 0; it < 5; it++) {
      int slot = it * 256 + t;
      int row = slot >> 5, ch = slot & 31;
      int j = row >> 3, hl = row & 7;
      int h = h0 + hl;
      size_t gpos = (size_t)j * 524288 + (size_t)h * 2048 + m0 +
                    ((ch & ~7) << 3) + (((ch & 7) ^ (h & 7)) << 3);
      *(uint4*)(Xft + gpos) = *(const uint4*)(&tx[row * 256 + ch * 8]);
    }
  } else {
    // Wft[j][h][h'] = s_j * sum_k W[h'][h][k] c_jk, swizzled (tiny)
    int h = b - 2304;
    int hp = t;
    const float4* p = (const float4*)(W + ((size_t)hp * 256 + h) * 8);
    float4 a = p[0], bb = p[1];
    float x[8] = {a.x, a.y, a.z, a.w, bb.x, bb.y, bb.z, bb.w};
    float F[5];
    fwd5(x, F);
    const float sc[5] = {0.125f, 0.25f, 0.25f, 0.25f, 0.125f};
    size_t pos = swz(h, hp, 256);
#pragma unroll
    for (int j = 0; j < 5; j++)
      Wft[(size_t)j * 65536 + pos] = (bf16_t)(F[j] * sc[j]);
  }
}

// Batched bf16 GEMM, 128 x BH tile, BK=64, 4 waves (64 x BH/2 each), 16x16x32
// MFMA. Swizzled operands; global_load_lds width-16 staging, double-buffered
// LDS, raw s_barrier + manual vmcnt so prefetch stays in flight across barriers.
template <typename OutT, bool SWZ_OUT, int BH>
__global__ __launch_bounds__(256) void gemm_lds(const bf16_t* __restrict__ A,
                                                const bf16_t* __restrict__ B,
                                                OutT* __restrict__ C, int K,
                                                size_t ap, size_t bp, size_t cp) {
  constexpr int WH = BH / 2;    // wave h-tile
  constexpr int NT = WH / 16;   // B frags / acc cols per wave
  constexpr int BR = BH / 32;   // B staging rounds (A rounds = 4)
  constexpr int ABUF = 128 * 64;
  constexpr int BBUF = BH * 64;
  __shared__ bf16_t sm[2 * ABUF + 2 * BBUF];  // A0 A1 B0 B1
  const int j = blockIdx.z;
  const bf16_t* Aj = A + (size_t)j * ap;
  const bf16_t* Bj = B + (size_t)j * bp;
  OutT* Cj = C + (size_t)j * cp;
  const int n0 = blockIdx.x * 128, h0 = blockIdx.y * BH;
  const int tid = threadIdx.x;
  const int wv = tid >> 6, ln = tid & 63;
  const int quad = ln >> 4, l16 = ln & 15;
  const int wn = (wv & 1) * 64, wh = (wv >> 1) * WH;

  const bf16_t* ga[4];
  int loA[4];
#pragma unroll
  for (int s = 0; s < 4; s++) {
    int slot = s * 256 + tid;
    int row = slot >> 3, c16 = slot & 7;
    ga[s] = Aj + (size_t)(n0 + row) * K + c16 * 8;
    loA[s] = (s * 256 + wv * 64) * 8;
  }
  const bf16_t* gb[BR];
  int loB[BR];
#pragma unroll
  for (int s = 0; s < BR; s++) {
    int slot = s * 256 + tid;
    int row = slot >> 3, c16 = slot & 7;
    gb[s] = Bj + (size_t)(h0 + row) * K + c16 * 8;
    loB[s] = (s * 256 + wv * 64) * 8;
  }

  // prologue: tile 0 -> buffer 0
#pragma unroll
  for (int s = 0; s < 4; s++) async_cp16(ga[s], sm + loA[s]);
#pragma unroll
  for (int s = 0; s < BR; s++) async_cp16(gb[s], sm + 2 * ABUF + loB[s]);

  f32x4 acc[4][NT] = {};
  for (int kk = 0; kk < K; kk += 64) {
    int p = (kk >> 6) & 1;
    if (kk + 64 < K) {
#pragma unroll
      for (int s = 0; s < 4; s++)
        async_cp16(ga[s] + kk + 64, sm + (p ^ 1) * ABUF + loA[s]);
#pragma unroll
      for (int s = 0; s < BR; s++)
        async_cp16(gb[s] + kk + 64, sm + 2 * ABUF + (p ^ 1) * BBUF + loB[s]);
      __builtin_amdgcn_s_waitcnt(0xF70 | (4 + BR));  // tile kk landed
    } else {
      __builtin_amdgcn_s_waitcnt(0xF70);  // vmcnt(0)
    }
    __builtin_amdgcn_s_barrier();
    const bf16_t* Asp = sm + p * ABUF;
    const bf16_t* Bsp = sm + 2 * ABUF + p * BBUF;
#pragma unroll
    for (int kh = 0; kh < 2; kh++) {
      bf16x8 af[4], bfr[NT];
      int c16 = kh * 4 + quad;
#pragma unroll
      for (int i = 0; i < 4; i++) {
        int ra = wn + i * 16 + l16;
        af[i] = *(const bf16x8*)(Asp + ra * 64 + ((c16 ^ (ra & 7)) << 3));
      }
#pragma unroll
      for (int t = 0; t < NT; t++) {
        int rb = wh + t * 16 + l16;
        bfr[t] = *(const bf16x8*)(Bsp + rb * 64 + ((c16 ^ (rb & 7)) << 3));
      }
#pragma unroll
      for (int i = 0; i < 4; i++)
#pragma unroll
        for (int t = 0; t < NT; t++)
          acc[i][t] = __builtin_amdgcn_mfma_f32_16x16x32_bf16(af[i], bfr[t],
                                                              acc[i][t], 0, 0, 0);
    }
    __builtin_amdgcn_s_barrier();  // protect buffer p^1 before next-iter DMA
  }
  // C/D layout: col = lane&15, row = quad*4 + reg
#pragma unroll
  for (int i = 0; i < 4; i++) {
#pragma unroll
    for (int t = 0; t < NT; t++) {
      int hc = h0 + wh + t * 16 + l16;
#pragma unroll
      for (int rg = 0; rg < 4; rg++) {
        int nr = n0 + wn + i * 16 + quad * 4 + rg;
        size_t off = SWZ_OUT ? swz(nr, hc, 256) : (size_t)nr * 256 + hc;
        Cj[off] = (OutT)acc[i][t][rg];
      }
    }
  }
}

// out[n][h][k] = sum_j c_jk * C2_j[n][h]  (ifft scales folded into Wft)
__global__ __launch_bounds__(256) void k_combine(const float* __restrict__ C2,
                                                 float* __restrict__ out) {
  size_t idx = (size_t)blockIdx.x * 256 + threadIdx.x;
  float c0 = C2[idx];
  float c1 = C2[524288 + idx];
  float c2 = C2[2 * 524288 + idx];
  float c3 = C2[3 * 524288 + idx];
  float c4 = C2[4 * 524288 + idx];
  float o0 = c0 + c1 + c2 + c3 + c4;
  float o4 = c0 - c1 + c2 - c3 + c4;
  float o2 = c0 - c2 + c4;
  float rt = R2C * (c1 - c3);
  float o1 = c0 + rt - c4;
  float o3 = c0 - rt - c4;
  float4* op = (float4*)(out + idx * 8);
  op[0] = make_float4(o0, o1, o2, o3);
  op[1] = make_float4(o4, o3, o2, o1);
}

extern "C" void kernel_launch(void* const* d_in, const int* in_sizes, int n_in,
                              void* d_out, int out_size, void* d_ws, size_t ws_size,
                              hipStream_t stream) {
  const float* X = (const float*)d_in[0];   // (2048,256,8)
  const float* A = (const float*)d_in[1];   // (2048,2048,8)
  const float* W = (const float*)d_in[2];   // (256,256,8)
  float* out = (float*)d_out;               // (2048,256,8)
  char* ws = (char*)d_ws;

  bf16_t* Af  = (bf16_t*)(ws);              // 5*2048*2048*2 = 41943040
  bf16_t* Xft = (bf16_t*)(ws + 41943040);   // 5*256*2048*2  =  5242880
  bf16_t* Wft = (bf16_t*)(ws + 47185920);   // 5*256*256*2   =   655360
  bf16_t* C1  = (bf16_t*)(ws + 47841280);   // 5*2048*256*2  =  5242880
  float*  C2  = (float*) (ws + 53084160);   // 5*2048*256*4  = 10485760
                                            // total 63569920 B

  k_pre<<<dim3(2560), 256, 0, stream>>>(X, A, W, Xft, Af, Wft);
  gemm_lds<bf16_t, true, 128><<<dim3(16, 2, 5), 256, 0, stream>>>(
      Af, Xft, C1, 2048, (size_t)4194304, (size_t)524288, (size_t)524288);
  gemm_lds<float, false, 128><<<dim3(16, 2, 5), 256, 0, stream>>>(
      C1, Wft, C2, 256, (size_t)524288, (size_t)65536, (size_t)524288);
  k_combine<<<dim3(2048), 256, 0, stream>>>(C2, out);
}